// Round 1
// baseline (435.917 us; speedup 1.0000x reference)
//
#include <hip/hip_runtime.h>

// LIF recurrence: V = V + alpha*(I - V); spike = V>=1.0; V=0 on spike.
// N=65536 neurons (parallel), T=1024 steps (sequential per neuron).
// Ideal HBM stream: 256 MB read + 256 MB write -> ~85 us at 6.3 TB/s.
//
// R2 changes vs R1 (425 us, 1.26 TB/s effective):
//  - TWO-PHASE split. R1 interleaved NT stores between load-issue and
//    load-wait; vmcnt retires in order, so every load-wait chained behind
//    the previous batch's store drain -> ~16k cycles/iter stall.
//  - Phase A: pure global-read + compute; spikes bit-packed (1 bit/step,
//    32-bit word per 32-step chunk) and staged in LDS (32 KB/block,
//    [word][tid] layout = conflict-free, lanes -> consecutive banks).
//    Loads double-buffered, U=32 -> 32-64 outstanding loads/wave.
//  - Phase B: pure store stream (bit -> 1.0f/0.0f expand), no waits --
//    the same structure as the rocclr fill kernel that hits 6.5 TB/s at
//    10% occupancy.
//  - V-update expression kept bit-identical to R1 (absmax was 0.0).

#define T_STEPS 1024
#define NUM_NEURONS 65536
#define N NUM_NEURONS
#define BLOCK 256
#define U 32                       // steps per chunk == bits per word
#define NCHUNK (T_STEPS / U)       // 32 chunks

__global__ __launch_bounds__(BLOCK) void lif_kernel(const float* __restrict__ in,
                                                    float* __restrict__ out) {
    __shared__ unsigned int words[NCHUNK][BLOCK];   // 32 KB / block

    const int tid = threadIdx.x;
    const int gid = blockIdx.x * BLOCK + tid;       // [0, 65536)
    constexpr float alpha = 0.05f;                  // DT/TAU = 1/20
    constexpr float vth = 1.0f;

    const float* __restrict__ p = in + gid;

    float V = 0.0f;                                 // V_RESET = 0
    float I[U], J[U];

    // prologue: load chunk 0
#pragma unroll
    for (int u = 0; u < U; ++u) I[u] = p[(size_t)u * N];

    // ---------------- Phase A: read + compute + LDS stage ----------------
    for (int k = 0; k < NCHUNK - 1; ++k) {
        // prefetch chunk k+1 (loads only -- nothing else enters vmcnt)
#pragma unroll
        for (int u = 0; u < U; ++u) J[u] = p[(size_t)((k + 1) * U + u) * N];

        unsigned int w = 0u;
#pragma unroll
        for (int u = 0; u < U; ++u) {
            V = V + alpha * (I[u] - V);             // reference order, V_RESET = 0
            const bool s = (V >= vth);
            w |= s ? (1u << u) : 0u;                // compile-time bit position
            V = s ? 0.0f : V;
        }
        words[k][tid] = w;

#pragma unroll
        for (int u = 0; u < U; ++u) I[u] = J[u];    // renamed away by regalloc
    }

    // epilogue chunk (no prefetch)
    {
        unsigned int w = 0u;
#pragma unroll
        for (int u = 0; u < U; ++u) {
            V = V + alpha * (I[u] - V);
            const bool s = (V >= vth);
            w |= s ? (1u << u) : 0u;
            V = s ? 0.0f : V;
        }
        words[NCHUNK - 1][tid] = w;
    }

    // ---------------- Phase B: pure store stream ----------------
    // Own-thread LDS roundtrip: lgkmcnt only, no barrier needed.
    float* __restrict__ q = out + gid;
    for (int k = 0; k < NCHUNK; ++k) {
        const unsigned int w = words[k][tid];
#pragma unroll
        for (int u = 0; u < U; ++u) {
            const float s = (w & (1u << u)) ? 1.0f : 0.0f;
            __builtin_nontemporal_store(s, q + (size_t)(k * U + u) * N);
        }
    }
}

extern "C" void kernel_launch(void* const* d_in, const int* in_sizes, int n_in,
                              void* d_out, int out_size, void* d_ws, size_t ws_size,
                              hipStream_t stream) {
    const float* in = (const float*)d_in[0];
    float* out = (float*)d_out;
    lif_kernel<<<NUM_NEURONS / BLOCK, BLOCK, 0, stream>>>(in, out);
}